// Round 4
// baseline (317.325 us; speedup 1.0000x reference)
//
#include <hip/hip_runtime.h>
#include <math.h>

#ifndef M_PI
#define M_PI 3.14159265358979323846
#endif

#define N_FFT       512
#define N_BINS      257
#define N_FILTERS   128
#define OUTPUT_SIZE 262144
#define N_TIMESTEPS 128

typedef int int4v __attribute__((ext_vector_type(4)));
typedef float f32x4 __attribute__((ext_vector_type(4)));

// ---- ordered-uint64 encoding for deterministic double atomic min/max ----
__device__ __forceinline__ unsigned long long enc_d(double f) {
    unsigned long long u = (unsigned long long)__double_as_longlong(f);
    return (u & 0x8000000000000000ull) ? ~u : (u | 0x8000000000000000ull);
}
__device__ __forceinline__ double dec_d(unsigned long long e) {
    unsigned long long u = (e & 0x8000000000000000ull) ? (e ^ 0x8000000000000000ull) : ~e;
    return __longlong_as_double((long long)u);
}

// ============================================================================
// K1a: DFT, one block per bin (257 blocks x 64 threads) — verified round 7.
// ============================================================================
__global__ __launch_bounds__(64) void k1a_dft(
    const float* __restrict__ audio, float* __restrict__ mag,
    unsigned long long* __restrict__ minmax)
{
    __shared__ double sre[64];
    __shared__ double sim[64];

    const int b    = blockIdx.x;     // bin 0..256
    const int lane = threadIdx.x;    // 0..63

    double re = 0.0, im = 0.0;
    #pragma unroll
    for (int j = 0; j < 8; ++j) {
        const int n = lane * 8 + j;              // rfft(n=512): first 512 samples
        const int m = (b * n) & (N_FFT - 1);
        double s, c;
        sincos((-2.0 * M_PI * (double)m) / (double)N_FFT, &s, &c);
        const double a = (double)audio[n];
        re += a * c;
        im += a * s;
    }
    sre[lane] = re;
    sim[lane] = im;
    __syncthreads();
    #pragma unroll
    for (int s = 32; s > 0; s >>= 1) {
        if (lane < s) {
            sre[lane] += sre[lane + s];
            sim[lane] += sim[lane + s];
        }
        __syncthreads();
    }
    if (lane == 0) {
        mag[b] = (float)sqrt(sre[0] * sre[0] + sim[0] * sim[0]);
        if (b == 0) {
            minmax[0] = 0xFFFFFFFFFFFFFFFFull;  // min slot
            minmax[1] = 0ull;                   // max slot
        }
    }
}

// ============================================================================
// K2: front-end epilogue (per-block redundant, deterministic) + GEMV.
//   ROUND 9 fix-up (round-3 failed on a macro token-collision: parameter `w`
//   also matched the `.w` component token -> `w2.w2`; renamed param to V and
//   switched to ext-vector [0..3] indexing).
//   Core change vs the 113 us baseline: force memory-level parallelism with
//   inline-asm loads (compiler collapsed source-level preloads, VGPR=36,
//   1.2 TB/s latency-bound):
//     - 16x asm volatile global_load_dwordx4 (issue-ordered, 256B/thread
//       in flight)
//     - "=&v" early-clobber so outputs can't alias the base address operand
//     - one s_waitcnt vmcnt(0)
//     - sched_barrier(0) so the register-only FMA chain can't be hoisted
//       above the waitcnt (guide rule #18)
//   Accumulation order unchanged (j ascending, comp 0..3, lo+hi combine) ->
//   bit-identical activity[].
// ============================================================================
__global__ __launch_bounds__(256) void k2_gemv(
    const f32x4* __restrict__ W4, const float* __restrict__ bias,
    const float* __restrict__ fb, const float* __restrict__ mag,
    const float* __restrict__ adapt, double* __restrict__ activity,
    unsigned long long* __restrict__ minmax)
{
    __shared__ float  magl[N_BINS];
    __shared__ double ad[N_FILTERS];
    __shared__ double red_min[256];
    __shared__ double red_max[256];

    const int tid = threadIdx.x;

    for (int j = tid; j < N_BINS; j += 256) magl[j] = mag[j];
    __syncthreads();

    if (tid < N_FILTERS) {
        const float* row = fb + tid * N_BINS;
        double acc = 0.0;
        int j = 0;
        #pragma unroll 1
        for (int b = 0; b < 8; ++b) {          // 8 x 32 = 256 bins
            float r[32];
            #pragma unroll
            for (int u = 0; u < 32; ++u) r[u] = row[j + u];
            #pragma unroll
            for (int u = 0; u < 32; ++u)
                acc += (double)r[u] * (double)magl[j + u];
            j += 32;
        }
        acc += (double)row[256] * (double)magl[256];   // remainder bin
        const double x = acc + 1e-6;               // + LATENCY_EPSILON
        const double p = pow(x, 0.3);
        const double a = p - (double)adapt[tid] * 0.5;
        ad[tid] = a > 0.0 ? a : 0.0;               // relu
    }
    __syncthreads();

    // ---- GEMV: 2 threads per row, 16 asm-forced float4 loads in flight ----
    const int gtid = blockIdx.x * 256 + tid;       // 0 .. 524287
    const int row  = gtid >> 1;
    const int half = gtid & 1;
    const float* base =
        (const float*)(W4 + (size_t)row * (N_FILTERS / 4) + half * 16);

    f32x4 w0, w1, w2, w3, w4, w5, w6, w7, w8, w9, w10, w11, w12, w13, w14, w15;
#define GLOAD(dst, OFF) \
    asm volatile("global_load_dwordx4 %0, %1, off offset:" OFF \
                 : "=&v"(dst) : "v"(base))
    GLOAD(w0,  "0");   GLOAD(w1,  "16");  GLOAD(w2,  "32");  GLOAD(w3,  "48");
    GLOAD(w4,  "64");  GLOAD(w5,  "80");  GLOAD(w6,  "96");  GLOAD(w7,  "112");
    GLOAD(w8,  "128"); GLOAD(w9,  "144"); GLOAD(w10, "160"); GLOAD(w11, "176");
    GLOAD(w12, "192"); GLOAD(w13, "208"); GLOAD(w14, "224"); GLOAD(w15, "240");
#undef GLOAD
    asm volatile("s_waitcnt vmcnt(0)" ::: "memory");
    __builtin_amdgcn_sched_barrier(0);

    const double* adh = ad + half * 64;
    double acc = 0.0;
#define ACC4(V, k) \
    acc += (double)V[0] * adh[(k)];     \
    acc += (double)V[1] * adh[(k) + 1]; \
    acc += (double)V[2] * adh[(k) + 2]; \
    acc += (double)V[3] * adh[(k) + 3];
    ACC4(w0,  0)  ACC4(w1,  4)  ACC4(w2,  8)  ACC4(w3,  12)
    ACC4(w4,  16) ACC4(w5,  20) ACC4(w6,  24) ACC4(w7,  28)
    ACC4(w8,  32) ACC4(w9,  36) ACC4(w10, 40) ACC4(w11, 44)
    ACC4(w12, 48) ACC4(w13, 52) ACC4(w14, 56) ACC4(w15, 60)
#undef ACC4

    // combine halves, deterministic lo+hi order (same value on both lanes)
    const double other = __shfl_xor(acc, 1, 64);
    const double lo = half ? other : acc;
    const double hi = half ? acc : other;
    const double a = (lo + hi) + (double)bias[row];
    if (!half) activity[row] = a;

    red_min[tid] = a;      // duplicated per pair — harmless for min/max
    red_max[tid] = a;
    __syncthreads();
    for (int s = 128; s > 0; s >>= 1) {
        if (tid < s) {
            red_min[tid] = fmin(red_min[tid], red_min[tid + s]);
            red_max[tid] = fmax(red_max[tid], red_max[tid + s]);
        }
        __syncthreads();
    }
    if (tid == 0) {
        atomicMin(&minmax[0], enc_d(red_min[0]));
        atomicMax(&minmax[1], enc_d(red_max[0]));
    }
}

// ============================================================================
// K3: latency coding + spike-matrix write (int32 out), fp64 quantization.
// ============================================================================
__global__ __launch_bounds__(256) void k3_spikes(
    const double* __restrict__ activity,
    const unsigned long long* __restrict__ minmax,
    int4v* __restrict__ out4)
{
    const int tid = blockIdx.x * 256 + threadIdx.x;  // 0..65535
    const double amin = dec_d(minmax[0]);
    const double amax = dec_d(minmax[1]);
    const double denom = (amax - amin) + 1e-6;

    const double nx = (activity[4 * tid + 0] - amin) / denom;
    const double ny = (activity[4 * tid + 1] - amin) / denom;
    const double nz = (activity[4 * tid + 2] - amin) / denom;
    const double nw = (activity[4 * tid + 3] - amin) / denom;

    const int lx = (int)((1.0 - nx) * 127.0);
    const int ly = (int)((1.0 - ny) * 127.0);
    const int lz = (int)((1.0 - nz) * 127.0);
    const int lw = (int)((1.0 - nw) * 127.0);

    const int vx = (nx > 0.05) ? 1 : 0;
    const int vy = (ny > 0.05) ? 1 : 0;
    const int vz = (nz > 0.05) ? 1 : 0;
    const int vw = (nw > 0.05) ? 1 : 0;

    const int t0 = blockIdx.y * (N_TIMESTEPS / 4);
    #pragma unroll 8
    for (int t = t0; t < t0 + N_TIMESTEPS / 4; ++t) {
        int4v v;
        v.x = (lx == t) ? vx : 0;
        v.y = (ly == t) ? vy : 0;
        v.z = (lz == t) ? vz : 0;
        v.w = (lw == t) ? vw : 0;
        out4[(size_t)t * (OUTPUT_SIZE / 4) + tid] = v;
    }
}

// ============================================================================
extern "C" void kernel_launch(void* const* d_in, const int* in_sizes, int n_in,
                              void* d_out, int out_size, void* d_ws, size_t ws_size,
                              hipStream_t stream) {
    (void)in_sizes; (void)n_in; (void)out_size; (void)ws_size;

    const float* audio = (const float*)d_in[0];   // [16000]
    const float* fb    = (const float*)d_in[1];   // [128, 257]
    const float* W     = (const float*)d_in[2];   // [262144, 128]
    const float* bias  = (const float*)d_in[3];   // [262144]
    const float* adapt = (const float*)d_in[4];   // [128]
    int* out = (int*)d_out;                       // [128, 262144] bool -> int32

    double* activity = (double*)d_ws;                              // 262144 f64
    unsigned long long* minmax =
        (unsigned long long*)(activity + OUTPUT_SIZE);             // 2 u64
    float* mag = (float*)(minmax + 2);                             // 257 f32

    k1a_dft<<<N_BINS, 64, 0, stream>>>(audio, mag, minmax);
    k2_gemv<<<OUTPUT_SIZE * 2 / 256, 256, 0, stream>>>(
        (const f32x4*)W, bias, fb, mag, adapt, activity, minmax);
    k3_spikes<<<dim3(OUTPUT_SIZE / 4 / 256, 4), 256, 0, stream>>>(
        activity, minmax, (int4v*)out);
}

// Round 6
// 268.680 us; speedup vs baseline: 1.1811x; 1.1811x over previous
//
#include <hip/hip_runtime.h>
#include <math.h>

#ifndef M_PI
#define M_PI 3.14159265358979323846
#endif

#define N_FFT       512
#define N_BINS      257
#define N_FILTERS   128
#define OUTPUT_SIZE 262144
#define N_TIMESTEPS 128

typedef int int4v __attribute__((ext_vector_type(4)));
typedef float f32x4 __attribute__((ext_vector_type(4)));

// ---- ordered-uint64 encoding for deterministic double atomic min/max ----
__device__ __forceinline__ unsigned long long enc_d(double f) {
    unsigned long long u = (unsigned long long)__double_as_longlong(f);
    return (u & 0x8000000000000000ull) ? ~u : (u | 0x8000000000000000ull);
}
__device__ __forceinline__ double dec_d(unsigned long long e) {
    unsigned long long u = (e & 0x8000000000000000ull) ? (e ^ 0x8000000000000000ull) : ~e;
    return __longlong_as_double((long long)u);
}

// ============================================================================
// K1a: DFT, one block per bin (257 blocks x 64 threads) — verified round 7.
// ============================================================================
__global__ __launch_bounds__(64) void k1a_dft(
    const float* __restrict__ audio, float* __restrict__ mag,
    unsigned long long* __restrict__ minmax)
{
    __shared__ double sre[64];
    __shared__ double sim[64];

    const int b    = blockIdx.x;     // bin 0..256
    const int lane = threadIdx.x;    // 0..63

    double re = 0.0, im = 0.0;
    #pragma unroll
    for (int j = 0; j < 8; ++j) {
        const int n = lane * 8 + j;              // rfft(n=512): first 512 samples
        const int m = (b * n) & (N_FFT - 1);
        double s, c;
        sincos((-2.0 * M_PI * (double)m) / (double)N_FFT, &s, &c);
        const double a = (double)audio[n];
        re += a * c;
        im += a * s;
    }
    sre[lane] = re;
    sim[lane] = im;
    __syncthreads();
    #pragma unroll
    for (int s = 32; s > 0; s >>= 1) {
        if (lane < s) {
            sre[lane] += sre[lane + s];
            sim[lane] += sim[lane + s];
        }
        __syncthreads();
    }
    if (lane == 0) {
        mag[b] = (float)sqrt(sre[0] * sre[0] + sim[0] * sim[0]);
        if (b == 0) {
            minmax[0] = 0xFFFFFFFFFFFFFFFFull;  // min slot
            minmax[1] = 0ull;                   // max slot
        }
    }
}

// ============================================================================
// K2: front-end epilogue (per-block redundant, deterministic) + GEMV.
//   ROUND 10 (re-run; round-5 bench was an infra timeout, kernel never ran):
//   4 independent rows per thread (register-blocked GEMV).
//   Evidence trail: R8 (C preload array) and R9 (16x asm loads) both
//   collapsed to a depth-1 serial load chain (VGPR 36/40, 1.1 TB/s,
//   32 x ~290cy L2/L3 latency per wave-row = measured dur). Root cause:
//   a SINGLE dependent accumulator chain gives the scheduler nothing to
//   overlap; it re-serializes any wide preload. Fix: 4 independent
//   accumulator chains per thread -> per-iteration loads are mutually
//   independent -> natural software pipelining (textbook register blocking).
//   Also: 2048 -> 256 blocks (8x fewer redundant prologues, 4096 -> 512
//   same-address atomics).
//   Numerics: per-row accumulation order unchanged (j ascending, comp 0..3,
//   fp64) -> activity[] bit-identical to the verified baseline. All locals
//   individually named (no runtime-indexed arrays -> no scratch).
// ============================================================================
__global__ __launch_bounds__(256) void k2_gemv(
    const f32x4* __restrict__ W4, const float* __restrict__ bias,
    const float* __restrict__ fb, const float* __restrict__ mag,
    const float* __restrict__ adapt, double* __restrict__ activity,
    unsigned long long* __restrict__ minmax)
{
    __shared__ float  magl[N_BINS];
    __shared__ double ad[N_FILTERS];
    __shared__ double red_min[256];
    __shared__ double red_max[256];

    const int tid = threadIdx.x;

    for (int j = tid; j < N_BINS; j += 256) magl[j] = mag[j];
    __syncthreads();

    if (tid < N_FILTERS) {
        const float* row = fb + tid * N_BINS;
        double acc = 0.0;
        int j = 0;
        #pragma unroll 1
        for (int b = 0; b < 8; ++b) {          // 8 x 32 = 256 bins
            float r[32];
            #pragma unroll
            for (int u = 0; u < 32; ++u) r[u] = row[j + u];
            #pragma unroll
            for (int u = 0; u < 32; ++u)
                acc += (double)r[u] * (double)magl[j + u];
            j += 32;
        }
        acc += (double)row[256] * (double)magl[256];   // remainder bin
        const double x = acc + 1e-6;               // + LATENCY_EPSILON
        const double p = pow(x, 0.3);
        const double a = p - (double)adapt[tid] * 0.5;
        ad[tid] = a > 0.0 ? a : 0.0;               // relu
    }
    __syncthreads();

    // ---- GEMV: 4 rows per thread, 4 independent accumulator chains ----
    const int t = blockIdx.x * 256 + tid;          // 0..65535
    const int r0 = t;
    const int r1 = t + 65536;
    const int r2 = t + 131072;
    const int r3 = t + 196608;
    const f32x4* p0 = W4 + (size_t)r0 * (N_FILTERS / 4);
    const f32x4* p1 = W4 + (size_t)r1 * (N_FILTERS / 4);
    const f32x4* p2 = W4 + (size_t)r2 * (N_FILTERS / 4);
    const f32x4* p3 = W4 + (size_t)r3 * (N_FILTERS / 4);

    double acc0 = 0.0, acc1 = 0.0, acc2 = 0.0, acc3 = 0.0;
    #pragma unroll 4
    for (int j = 0; j < N_FILTERS / 4; ++j) {
        const f32x4 wa = p0[j];
        const f32x4 wb = p1[j];
        const f32x4 wc = p2[j];
        const f32x4 wd = p3[j];
        const int k = j * 4;
        acc0 += (double)wa[0] * ad[k];
        acc0 += (double)wa[1] * ad[k + 1];
        acc0 += (double)wa[2] * ad[k + 2];
        acc0 += (double)wa[3] * ad[k + 3];
        acc1 += (double)wb[0] * ad[k];
        acc1 += (double)wb[1] * ad[k + 1];
        acc1 += (double)wb[2] * ad[k + 2];
        acc1 += (double)wb[3] * ad[k + 3];
        acc2 += (double)wc[0] * ad[k];
        acc2 += (double)wc[1] * ad[k + 1];
        acc2 += (double)wc[2] * ad[k + 2];
        acc2 += (double)wc[3] * ad[k + 3];
        acc3 += (double)wd[0] * ad[k];
        acc3 += (double)wd[1] * ad[k + 1];
        acc3 += (double)wd[2] * ad[k + 2];
        acc3 += (double)wd[3] * ad[k + 3];
    }

    const double a0 = acc0 + (double)bias[r0];
    const double a1 = acc1 + (double)bias[r1];
    const double a2 = acc2 + (double)bias[r2];
    const double a3 = acc3 + (double)bias[r3];
    activity[r0] = a0;
    activity[r1] = a1;
    activity[r2] = a2;
    activity[r3] = a3;

    const double mn = fmin(fmin(a0, a1), fmin(a2, a3));
    const double mx = fmax(fmax(a0, a1), fmax(a2, a3));
    red_min[tid] = mn;
    red_max[tid] = mx;
    __syncthreads();
    for (int s = 128; s > 0; s >>= 1) {
        if (tid < s) {
            red_min[tid] = fmin(red_min[tid], red_min[tid + s]);
            red_max[tid] = fmax(red_max[tid], red_max[tid + s]);
        }
        __syncthreads();
    }
    if (tid == 0) {
        atomicMin(&minmax[0], enc_d(red_min[0]));
        atomicMax(&minmax[1], enc_d(red_max[0]));
    }
}

// ============================================================================
// K3: latency coding + spike-matrix write (int32 out), fp64 quantization.
// ============================================================================
__global__ __launch_bounds__(256) void k3_spikes(
    const double* __restrict__ activity,
    const unsigned long long* __restrict__ minmax,
    int4v* __restrict__ out4)
{
    const int tid = blockIdx.x * 256 + threadIdx.x;  // 0..65535
    const double amin = dec_d(minmax[0]);
    const double amax = dec_d(minmax[1]);
    const double denom = (amax - amin) + 1e-6;

    const double nx = (activity[4 * tid + 0] - amin) / denom;
    const double ny = (activity[4 * tid + 1] - amin) / denom;
    const double nz = (activity[4 * tid + 2] - amin) / denom;
    const double nw = (activity[4 * tid + 3] - amin) / denom;

    const int lx = (int)((1.0 - nx) * 127.0);
    const int ly = (int)((1.0 - ny) * 127.0);
    const int lz = (int)((1.0 - nz) * 127.0);
    const int lw = (int)((1.0 - nw) * 127.0);

    const int vx = (nx > 0.05) ? 1 : 0;
    const int vy = (ny > 0.05) ? 1 : 0;
    const int vz = (nz > 0.05) ? 1 : 0;
    const int vw = (nw > 0.05) ? 1 : 0;

    const int t0 = blockIdx.y * (N_TIMESTEPS / 4);
    #pragma unroll 8
    for (int t = t0; t < t0 + N_TIMESTEPS / 4; ++t) {
        int4v v;
        v.x = (lx == t) ? vx : 0;
        v.y = (ly == t) ? vy : 0;
        v.z = (lz == t) ? vz : 0;
        v.w = (lw == t) ? vw : 0;
        out4[(size_t)t * (OUTPUT_SIZE / 4) + tid] = v;
    }
}

// ============================================================================
extern "C" void kernel_launch(void* const* d_in, const int* in_sizes, int n_in,
                              void* d_out, int out_size, void* d_ws, size_t ws_size,
                              hipStream_t stream) {
    (void)in_sizes; (void)n_in; (void)out_size; (void)ws_size;

    const float* audio = (const float*)d_in[0];   // [16000]
    const float* fb    = (const float*)d_in[1];   // [128, 257]
    const float* W     = (const float*)d_in[2];   // [262144, 128]
    const float* bias  = (const float*)d_in[3];   // [262144]
    const float* adapt = (const float*)d_in[4];   // [128]
    int* out = (int*)d_out;                       // [128, 262144] bool -> int32

    double* activity = (double*)d_ws;                              // 262144 f64
    unsigned long long* minmax =
        (unsigned long long*)(activity + OUTPUT_SIZE);             // 2 u64
    float* mag = (float*)(minmax + 2);                             // 257 f32

    k1a_dft<<<N_BINS, 64, 0, stream>>>(audio, mag, minmax);
    k2_gemv<<<OUTPUT_SIZE / 1024, 256, 0, stream>>>(
        (const f32x4*)W, bias, fb, mag, adapt, activity, minmax);
    k3_spikes<<<dim3(OUTPUT_SIZE / 4 / 256, 4), 256, 0, stream>>>(
        activity, minmax, (int4v*)out);
}